// Round 12
// baseline (597.506 us; speedup 1.0000x reference)
//
#include <hip/hip_runtime.h>
#include <hip/hip_bf16.h>
#include <math.h>

#define N_NODES 50000
#define N_EDGES 800000
#define D0 64
#define D1 128
#define D2 40

#define NB  256   // buckets
#define NPB 196   // nodes per bucket (256*196 = 50176 >= 50000)

typedef short s16x8 __attribute__((ext_vector_type(8)));
typedef float f32x4 __attribute__((ext_vector_type(4)));

static __device__ __forceinline__ unsigned short f2bf(float v) {
    __hip_bfloat16 hb = __float2bfloat16(v);
    return *(unsigned short*)&hb;
}
static __device__ __forceinline__ float bf_lo(unsigned u) { return __uint_as_float(u << 16); }
static __device__ __forceinline__ float bf_hi(unsigned u) { return __uint_as_float(u & 0xffff0000u); }

// ---------------- fused prep: bucket histogram + cast x + pack weights ----------------
__global__ __launch_bounds__(256) void prep_kernel(
        const float* __restrict__ x, const int* __restrict__ dst,
        const float* __restrict__ W1l, const float* __restrict__ W1r,
        const float* __restrict__ W2l, const float* __restrict__ W2r,
        unsigned short* __restrict__ xh, int* __restrict__ hist,
        unsigned short* __restrict__ wpk1, unsigned short* __restrict__ wpk2,
        int E, int nCount, int nCast) {
    int b = blockIdx.x, t = threadIdx.x;
    if (b < nCount) {
        __shared__ int h[NB];
        h[t] = 0;
        __syncthreads();
        int e0 = b * 2048;
        for (int i = t; i < 2048; i += 256) {
            int e = e0 + i;
            if (e < E) atomicAdd(&h[(unsigned)dst[e] / NPB], 1);
        }
        __syncthreads();
        hist[b * NB + t] = h[t];
    } else if (b < nCount + nCast) {
        int i = ((b - nCount) * 256 + t) * 4;   // nCast*1024 == N*D0 exactly
        float4 v = *(const float4*)(x + i);
        unsigned o0 = (unsigned)f2bf(v.x) | ((unsigned)f2bf(v.y) << 16);
        unsigned o1 = (unsigned)f2bf(v.z) | ((unsigned)f2bf(v.w) << 16);
        uint2 pk; pk.x = o0; pk.y = o1;
        *(uint2*)(xh + i) = pk;
    } else if (b < nCount + nCast + 8) {
        int f = (b - nCount - nCast) * 4 + (t >> 6);   // 0..31
        int lane = t & 63;
        int nt = f & 7;
        int col = nt * 16 + (lane & 15);
        int kbase = (f >> 3) * 32 + (lane >> 4) * 8;
        unsigned short* o = wpk1 + ((size_t)f * 64 + lane) * 8;
#pragma unroll
        for (int j = 0; j < 8; ++j) {
            int k = kbase + j;
            float w = (k < 64) ? W1r[k * 128 + col] : W1l[(k - 64) * 128 + col];
            o[j] = f2bf(w);
        }
    } else {
        int f = (b - nCount - nCast - 8) * 4 + (t >> 6);   // 0..19
        if (f < 20) {
            int lane = t & 63;
            int nt = f % 5;
            int col = nt * 16 + (lane & 15);       // 0..79
            int kbase = (f / 5) * 32 + (lane >> 4) * 8;
            unsigned short* o = wpk2 + ((size_t)f * 64 + lane) * 8;
#pragma unroll
            for (int j = 0; j < 8; ++j) {
                int k = kbase + j;
                float w = (col < 40) ? W2l[k * 40 + col] : W2r[k * 40 + (col - 40)];
                o[j] = f2bf(w);
            }
        }
    }
}

// ---------------- scan: column-sum hist + exclusive scan -> bbase/bcursor ----------------
__global__ void bucket_scan_kernel(const int* __restrict__ hist, int nCount,
                                   int* __restrict__ bbase, int* __restrict__ bcursor) {
    __shared__ int sd[NB];
    int t = threadIdx.x;
    int v = 0;
#pragma unroll 4
    for (int b = 0; b < nCount; ++b) v += hist[b * NB + t];
    sd[t] = v;
    __syncthreads();
    for (int off = 1; off < NB; off <<= 1) {
        int u = (t >= off) ? sd[t - off] : 0;
        __syncthreads();
        sd[t] += u;
        __syncthreads();
    }
    int ex = sd[t] - v;
    bbase[t] = ex;
    bcursor[t] = ex;
}

// ---------------- scatter edges into bucket regions as packed (local_dst<<17 | src) -------
__global__ __launch_bounds__(256) void bucket_scatter_kernel(
        const int* __restrict__ src, const int* __restrict__ dst,
        int* __restrict__ bcursor, unsigned* __restrict__ ebuf, int E) {
    __shared__ int h[NB];
    __shared__ int base[NB];
    int t = threadIdx.x;
    int e0 = blockIdx.x * 4096;
    h[t] = 0;
    __syncthreads();
    for (int i = t; i < 4096; i += 256) {
        int e = e0 + i;
        if (e < E) atomicAdd(&h[(unsigned)dst[e] / NPB], 1);
    }
    __syncthreads();
    if (h[t] > 0) base[t] = atomicAdd(&bcursor[t], h[t]);
    h[t] = 0;
    __syncthreads();
    for (int i = t; i < 4096; i += 256) {
        int e = e0 + i;
        if (e < E) {
            unsigned d = (unsigned)dst[e];
            unsigned b = d / NPB;
            unsigned ld = d - b * NPB;
            int k = atomicAdd(&h[b], 1);
            ebuf[base[b] + k] = (ld << 17) | (unsigned)src[e];
        }
    }
}

// ---------------- agg1 per-bucket: stream ebuf, accumulate in LDS, emit bf16 -------------
__global__ __launch_bounds__(256) void agg1_bucket_kernel(
        const unsigned* __restrict__ ebuf, const int* __restrict__ bbase,
        const unsigned short* __restrict__ xh, unsigned short* __restrict__ aggh,
        int E, int N) {
    __shared__ float acc[NPB * 68];
    __shared__ int dcnt[NPB];
    int b = blockIdx.x, t = threadIdx.x;
    for (int i = t; i < NPB * 68; i += 256) acc[i] = 0.f;
    for (int i = t; i < NPB; i += 256) dcnt[i] = 0;
    __syncthreads();
    int s0 = bbase[b];
    int s1 = (b < NB - 1) ? bbase[b + 1] : E;
    int w = t >> 6, lane = t & 63;
    int es = lane >> 3, l = lane & 7;         // 8 edges x 8 feat-chunks per wave group
    for (int base = s0 + w * 16; base < s1; base += 64) {
        int e0 = base + es, e1 = base + 8 + es;
        bool v0 = e0 < s1, v1 = e1 < s1;
        unsigned pk0 = v0 ? ebuf[e0] : 0u;
        unsigned pk1 = v1 ? ebuf[e1] : 0u;
        uint4 g0, g1;
        if (v0) g0 = *(const uint4*)(xh + (size_t)(pk0 & 0x1FFFFu) * D0 + l * 8);
        if (v1) g1 = *(const uint4*)(xh + (size_t)(pk1 & 0x1FFFFu) * D0 + l * 8);
        if (v0) {
            float* ap = &acc[(pk0 >> 17) * 68 + l * 8];
            atomicAdd(ap + 0, bf_lo(g0.x)); atomicAdd(ap + 1, bf_hi(g0.x));
            atomicAdd(ap + 2, bf_lo(g0.y)); atomicAdd(ap + 3, bf_hi(g0.y));
            atomicAdd(ap + 4, bf_lo(g0.z)); atomicAdd(ap + 5, bf_hi(g0.z));
            atomicAdd(ap + 6, bf_lo(g0.w)); atomicAdd(ap + 7, bf_hi(g0.w));
            if (l == 0) atomicAdd(&dcnt[pk0 >> 17], 1);
        }
        if (v1) {
            float* ap = &acc[(pk1 >> 17) * 68 + l * 8];
            atomicAdd(ap + 0, bf_lo(g1.x)); atomicAdd(ap + 1, bf_hi(g1.x));
            atomicAdd(ap + 2, bf_lo(g1.y)); atomicAdd(ap + 3, bf_hi(g1.y));
            atomicAdd(ap + 4, bf_lo(g1.z)); atomicAdd(ap + 5, bf_hi(g1.z));
            atomicAdd(ap + 6, bf_lo(g1.w)); atomicAdd(ap + 7, bf_hi(g1.w));
            if (l == 0) atomicAdd(&dcnt[pk1 >> 17], 1);
        }
    }
    __syncthreads();
    for (int i = t; i < NPB * 8; i += 256) {
        int n = i >> 3, c = i & 7;
        int gn = b * NPB + n;
        if (gn < N) {
            float inv = 1.f / (float)max(dcnt[n], 1);
            const float* ap = &acc[n * 68 + c * 8];
            uint4 pk;
            pk.x = (unsigned)f2bf(ap[0] * inv) | ((unsigned)f2bf(ap[1] * inv) << 16);
            pk.y = (unsigned)f2bf(ap[2] * inv) | ((unsigned)f2bf(ap[3] * inv) << 16);
            pk.z = (unsigned)f2bf(ap[4] * inv) | ((unsigned)f2bf(ap[5] * inv) << 16);
            pk.w = (unsigned)f2bf(ap[6] * inv) | ((unsigned)f2bf(ap[7] * inv) << 16);
            *(uint4*)(aggh + (size_t)gn * D0 + c * 8) = pk;
        }
    }
}

// ---------------- agg2 per-bucket + fused log_softmax ----------------
// out[v] = r2[v] + mean p2[src]; out2[v] = log_softmax(out[v]).
__global__ __launch_bounds__(256) void agg2_bucket_kernel(
        const unsigned* __restrict__ ebuf, const int* __restrict__ bbase,
        const unsigned short* __restrict__ p2h, const float* __restrict__ r2,
        float* __restrict__ out, float* __restrict__ out2, int E, int N) {
    __shared__ float acc[NPB * 44];
    __shared__ int dcnt[NPB];
    int b = blockIdx.x, t = threadIdx.x;
    for (int i = t; i < NPB * 44; i += 256) acc[i] = 0.f;
    for (int i = t; i < NPB; i += 256) dcnt[i] = 0;
    __syncthreads();
    int s0 = bbase[b];
    int s1 = (b < NB - 1) ? bbase[b + 1] : E;
    int w = t >> 6, lane = t & 63;
    int es = lane / 5, l5 = lane - es * 5;    // 12 edges x 5 feat-chunks (lanes 60..63 idle)
    bool lv = es < 12;
    for (int base = s0 + w * 24; base < s1; base += 96) {
        int e0 = base + es, e1 = base + 12 + es;
        bool v0 = lv && (e0 < s1), v1 = lv && (e1 < s1);
        unsigned pk0 = v0 ? ebuf[e0] : 0u;
        unsigned pk1 = v1 ? ebuf[e1] : 0u;
        uint4 g0, g1;
        if (v0) g0 = *(const uint4*)(p2h + (size_t)(pk0 & 0x1FFFFu) * D2 + l5 * 8);
        if (v1) g1 = *(const uint4*)(p2h + (size_t)(pk1 & 0x1FFFFu) * D2 + l5 * 8);
        if (v0) {
            float* ap = &acc[(pk0 >> 17) * 44 + l5 * 8];
            atomicAdd(ap + 0, bf_lo(g0.x)); atomicAdd(ap + 1, bf_hi(g0.x));
            atomicAdd(ap + 2, bf_lo(g0.y)); atomicAdd(ap + 3, bf_hi(g0.y));
            atomicAdd(ap + 4, bf_lo(g0.z)); atomicAdd(ap + 5, bf_hi(g0.z));
            atomicAdd(ap + 6, bf_lo(g0.w)); atomicAdd(ap + 7, bf_hi(g0.w));
            if (l5 == 0) atomicAdd(&dcnt[pk0 >> 17], 1);
        }
        if (v1) {
            float* ap = &acc[(pk1 >> 17) * 44 + l5 * 8];
            atomicAdd(ap + 0, bf_lo(g1.x)); atomicAdd(ap + 1, bf_hi(g1.x));
            atomicAdd(ap + 2, bf_lo(g1.y)); atomicAdd(ap + 3, bf_hi(g1.y));
            atomicAdd(ap + 4, bf_lo(g1.z)); atomicAdd(ap + 5, bf_hi(g1.z));
            atomicAdd(ap + 6, bf_lo(g1.w)); atomicAdd(ap + 7, bf_hi(g1.w));
            if (l5 == 0) atomicAdd(&dcnt[pk1 >> 17], 1);
        }
    }
    __syncthreads();
    // finalize + log_softmax: wave handles 6 nodes (10 lanes each, lanes 60..63 idle)
    // Disjoint reduction tree over 10 lanes (correct for sum AND max):
    //   1) l10<5: v += shfl(+5)   -> lanes 0..4 hold disjoint pairs (i, i+5)
    //   2) l10<2: v += shfl(+2)   -> lane0 {0,2}, lane1 {1,3}
    //   3) l10==0: v += shfl(+1)  -> lane0 {0,1,2,3}
    //   4) l10==0: v += shfl(+4)  -> lane0 {0..9} (adds lane4 = {4,9})
    int g = lane / 10, l10 = lane - g * 10;
    for (int n0 = w * 6; n0 < NPB; n0 += 24) {
        int n = n0 + g;
        int gn = b * NPB + n;
        bool act = (g < 6) && (n < NPB) && (gn < N);
        float4 h2 = {0.f, 0.f, 0.f, 0.f};
        if (act) {
            float inv = 1.f / (float)max(dcnt[n], 1);
            float4 rr = *(const float4*)(r2 + (size_t)gn * D2 + l10 * 4);
            const float* ap = &acc[n * 44 + l10 * 4];
            h2.x = rr.x + ap[0] * inv; h2.y = rr.y + ap[1] * inv;
            h2.z = rr.z + ap[2] * inv; h2.w = rr.w + ap[3] * inv;
            *(float4*)(out + (size_t)gn * D2 + l10 * 4) = h2;
        }
        float m = act ? fmaxf(fmaxf(h2.x, h2.y), fmaxf(h2.z, h2.w)) : -INFINITY;
        float tmp;
        tmp = __shfl(m, lane + 5); if (l10 < 5) m = fmaxf(m, tmp);
        tmp = __shfl(m, lane + 2); if (l10 < 2) m = fmaxf(m, tmp);
        tmp = __shfl(m, lane + 1); if (l10 == 0) m = fmaxf(m, tmp);
        tmp = __shfl(m, lane + 4); if (l10 == 0) m = fmaxf(m, tmp);
        m = __shfl(m, g * 10);
        float s = act ? (expf(h2.x - m) + expf(h2.y - m) + expf(h2.z - m) + expf(h2.w - m)) : 0.f;
        tmp = __shfl(s, lane + 5); if (l10 < 5) s += tmp;
        tmp = __shfl(s, lane + 2); if (l10 < 2) s += tmp;
        tmp = __shfl(s, lane + 1); if (l10 == 0) s += tmp;
        tmp = __shfl(s, lane + 4); if (l10 == 0) s += tmp;
        s = __shfl(s, g * 10);
        if (act) {
            float lg = m + logf(s);
            float4 o; o.x = h2.x - lg; o.y = h2.y - lg; o.z = h2.z - lg; o.w = h2.w - lg;
            *(float4*)(out2 + (size_t)gn * D2 + l10 * 4) = o;
        }
    }
}

// ---------------- GEMM 1 (MFMA): h = relu([x|agg]@[W1r;W1l] + b1), bf16 in/out ----------------
__global__ __launch_bounds__(256) void gemm1_mfma(
        const unsigned short* __restrict__ xh, const unsigned short* __restrict__ aggh,
        const unsigned short* __restrict__ Wpk, const float* __restrict__ b1,
        unsigned short* __restrict__ h, int N) {
    __shared__ __align__(16) unsigned short As[128 * 136];  // [row][k], +8 pad
    int t = threadIdx.x;
    int r0 = blockIdx.x * 128;
    for (int i = t; i < 2048; i += 256) {
        int r = i >> 4, c = i & 15;
        int gr = r0 + r; gr = (gr < N) ? gr : (N - 1);
        uint4 v = (c < 8) ? ((const uint4*)(xh + (size_t)gr * 64))[c]
                          : ((const uint4*)(aggh + (size_t)gr * 64))[c - 8];
        *(uint4*)(As + r * 136 + c * 8) = v;
    }
    __syncthreads();
    int w = t >> 6, lane = t & 63;
    int l15 = lane & 15, q = lane >> 4;
    f32x4 zero = {0.f, 0.f, 0.f, 0.f};
    f32x4 acc[2][8];
#pragma unroll
    for (int rt = 0; rt < 2; ++rt)
#pragma unroll
        for (int nt = 0; nt < 8; ++nt) acc[rt][nt] = zero;
    const unsigned short* abase = As + (w * 32 + l15) * 136 + q * 8;
#pragma unroll
    for (int ks = 0; ks < 4; ++ks) {
        s16x8 a0 = *(const s16x8*)(abase + ks * 32);
        s16x8 a1 = *(const s16x8*)(abase + 16 * 136 + ks * 32);
        s16x8 b[8];
#pragma unroll
        for (int nt = 0; nt < 8; ++nt)
            b[nt] = *(const s16x8*)(Wpk + ((size_t)(ks * 8 + nt) * 64 + lane) * 8);
#pragma unroll
        for (int nt = 0; nt < 8; ++nt) {
            acc[0][nt] = __builtin_amdgcn_mfma_f32_16x16x32_bf16(a0, b[nt], acc[0][nt], 0, 0, 0);
            acc[1][nt] = __builtin_amdgcn_mfma_f32_16x16x32_bf16(a1, b[nt], acc[1][nt], 0, 0, 0);
        }
    }
    int rbase = r0 + w * 32 + q * 4;
#pragma unroll
    for (int nt = 0; nt < 8; ++nt) {
        int col = nt * 16 + l15;
        float bias = b1[col];
#pragma unroll
        for (int rt = 0; rt < 2; ++rt) {
#pragma unroll
            for (int reg = 0; reg < 4; ++reg) {
                int row = rbase + rt * 16 + reg;
                if (row < N)
                    h[(size_t)row * 128 + col] = f2bf(fmaxf(acc[rt][nt][reg] + bias, 0.f));
            }
        }
    }
}

// ---------------- GEMM 2 (MFMA): p2h(bf16) = h@W2l, r2(f32) = h@W2r + b2 ----------------
__global__ __launch_bounds__(256) void gemm2_mfma(
        const unsigned short* __restrict__ hq, const unsigned short* __restrict__ Wpk,
        const float* __restrict__ b2,
        unsigned short* __restrict__ p2h, float* __restrict__ r2, int N) {
    __shared__ __align__(16) unsigned short As[128 * 136];
    int t = threadIdx.x;
    int r0 = blockIdx.x * 128;
    for (int i = t; i < 2048; i += 256) {
        int r = i >> 4, c = i & 15;
        int gr = r0 + r; gr = (gr < N) ? gr : (N - 1);
        uint4 v = ((const uint4*)(hq + (size_t)gr * 128))[c];
        *(uint4*)(As + r * 136 + c * 8) = v;
    }
    __syncthreads();
    int w = t >> 6, lane = t & 63;
    int l15 = lane & 15, q = lane >> 4;
    f32x4 zero = {0.f, 0.f, 0.f, 0.f};
    f32x4 acc[2][5];
#pragma unroll
    for (int rt = 0; rt < 2; ++rt)
#pragma unroll
        for (int nt = 0; nt < 5; ++nt) acc[rt][nt] = zero;
    const unsigned short* abase = As + (w * 32 + l15) * 136 + q * 8;
#pragma unroll
    for (int ks = 0; ks < 4; ++ks) {
        s16x8 a0 = *(const s16x8*)(abase + ks * 32);
        s16x8 a1 = *(const s16x8*)(abase + 16 * 136 + ks * 32);
        s16x8 b[5];
#pragma unroll
        for (int nt = 0; nt < 5; ++nt)
            b[nt] = *(const s16x8*)(Wpk + ((size_t)(ks * 5 + nt) * 64 + lane) * 8);
#pragma unroll
        for (int nt = 0; nt < 5; ++nt) {
            acc[0][nt] = __builtin_amdgcn_mfma_f32_16x16x32_bf16(a0, b[nt], acc[0][nt], 0, 0, 0);
            acc[1][nt] = __builtin_amdgcn_mfma_f32_16x16x32_bf16(a1, b[nt], acc[1][nt], 0, 0, 0);
        }
    }
    int rbase = r0 + w * 32 + q * 4;
#pragma unroll
    for (int nt = 0; nt < 5; ++nt) {
        int col = nt * 16 + l15;   // 0..79
        bool isp = col < 40;
        int oc = isp ? col : (col - 40);
        float bias = isp ? 0.f : b2[oc];
#pragma unroll
        for (int rt = 0; rt < 2; ++rt) {
#pragma unroll
            for (int reg = 0; reg < 4; ++reg) {
                int row = rbase + rt * 16 + reg;
                if (row < N) {
                    float v = acc[rt][nt][reg] + bias;
                    if (isp) p2h[(size_t)row * 40 + oc] = f2bf(v);
                    else     r2[(size_t)row * 40 + oc] = v;
                }
            }
        }
    }
}

// ---------------- launch ----------------

extern "C" void kernel_launch(void* const* d_in, const int* in_sizes, int n_in,
                              void* d_out, int out_size, void* d_ws, size_t ws_size,
                              hipStream_t stream) {
    const float* x   = (const float*)d_in[0];
    const int*   ei  = (const int*)d_in[1];
    const float* W1l = (const float*)d_in[2];
    const float* W1r = (const float*)d_in[3];
    const float* b1  = (const float*)d_in[4];
    const float* W2l = (const float*)d_in[5];
    const float* W2r = (const float*)d_in[6];
    const float* b2  = (const float*)d_in[7];
    float* out = (float*)d_out;

    const int N = N_NODES;
    const int E = in_sizes[1] / 2;
    const int* src = ei;
    const int* dst = ei + E;

    char* p = (char*)d_ws;
    auto alloc = [&](size_t bytes) -> void* {
        void* r = (void*)p;
        p += (bytes + 255) & ~(size_t)255;
        return r;
    };
    const int nCount = (E + 2047) / 2048;          // 391
    const int nCast  = (N * D0) / 1024;            // 3125 (exact)

    unsigned* ebuf    = (unsigned*)alloc((size_t)E * 4);
    int*      hist    = (int*)alloc((size_t)nCount * NB * 4);
    int*      bbase   = (int*)alloc(NB * 4);
    int*      bcursor = (int*)alloc(NB * 4);
    unsigned short* xh    = (unsigned short*)alloc((size_t)N * D0 * 2);
    unsigned short* aggh  = (unsigned short*)alloc((size_t)N * D0 * 2);
    unsigned short* hbuf  = (unsigned short*)alloc((size_t)N * D1 * 2);
    unsigned short* wpk1  = (unsigned short*)alloc((size_t)32 * 64 * 8 * 2);
    unsigned short* wpk2  = (unsigned short*)alloc((size_t)20 * 64 * 8 * 2);
    unsigned short* p2h   = (unsigned short*)alloc((size_t)N * D2 * 2);
    float* r2buf = (float*)alloc((size_t)N * D2 * 4);

    // prep (hist + cast + pack) -> scan -> scatter (no CSR fill needed)
    prep_kernel<<<nCount + nCast + 8 + 5, 256, 0, stream>>>(
        x, dst, W1l, W1r, W2l, W2r, xh, hist, wpk1, wpk2, E, nCount, nCast);
    bucket_scan_kernel<<<1, NB, 0, stream>>>(hist, nCount, bbase, bcursor);
    bucket_scatter_kernel<<<(E + 4095) / 4096, 256, 0, stream>>>(src, dst, bcursor, ebuf, E);

    // layer 1: per-bucket LDS aggregation, then MFMA GEMM
    agg1_bucket_kernel<<<NB, 256, 0, stream>>>(ebuf, bbase, xh, aggh, E, N);
    gemm1_mfma<<<(N + 127) / 128, 256, 0, stream>>>(xh, aggh, wpk1, b1, hbuf, N);

    // layer 2: project first (linearity), per-bucket aggregation + fused log_softmax
    gemm2_mfma<<<(N + 127) / 128, 256, 0, stream>>>(hbuf, wpk2, b2, p2h, r2buf, N);
    agg2_bucket_kernel<<<NB, 256, 0, stream>>>(ebuf, bbase, p2h, r2buf,
                                               out, out + (size_t)N * D2, E, N);
}

// Round 13
// 201.075 us; speedup vs baseline: 2.9716x; 2.9716x over previous
//
#include <hip/hip_runtime.h>
#include <hip/hip_bf16.h>
#include <math.h>

#define N_NODES 50000
#define N_EDGES 800000
#define D0 64
#define D1 128
#define D2 40

#define NB  256   // buckets
#define NPB 196   // nodes per bucket (256*196 = 50176 >= 50000)

typedef short s16x8 __attribute__((ext_vector_type(8)));
typedef float f32x4 __attribute__((ext_vector_type(4)));

static __device__ __forceinline__ unsigned short f2bf(float v) {
    __hip_bfloat16 hb = __float2bfloat16(v);
    return *(unsigned short*)&hb;
}

// ---------------- fused prep: bucket histogram + cast x + pack weights ----------------
__global__ __launch_bounds__(256) void prep_kernel(
        const float* __restrict__ x, const int* __restrict__ dst,
        const float* __restrict__ W1l, const float* __restrict__ W1r,
        const float* __restrict__ W2l, const float* __restrict__ W2r,
        unsigned short* __restrict__ xh, int* __restrict__ hist,
        unsigned short* __restrict__ wpk1, unsigned short* __restrict__ wpk2,
        int E, int nCount, int nCast) {
    int b = blockIdx.x, t = threadIdx.x;
    if (b < nCount) {
        __shared__ int h[NB];
        h[t] = 0;
        __syncthreads();
        int e0 = b * 2048;
        for (int i = t; i < 2048; i += 256) {
            int e = e0 + i;
            if (e < E) atomicAdd(&h[(unsigned)dst[e] / NPB], 1);
        }
        __syncthreads();
        hist[b * NB + t] = h[t];
    } else if (b < nCount + nCast) {
        int i = ((b - nCount) * 256 + t) * 4;   // nCast*1024 == N*D0 exactly
        float4 v = *(const float4*)(x + i);
        unsigned o0 = (unsigned)f2bf(v.x) | ((unsigned)f2bf(v.y) << 16);
        unsigned o1 = (unsigned)f2bf(v.z) | ((unsigned)f2bf(v.w) << 16);
        uint2 pk; pk.x = o0; pk.y = o1;
        *(uint2*)(xh + i) = pk;
    } else if (b < nCount + nCast + 8) {
        int f = (b - nCount - nCast) * 4 + (t >> 6);   // 0..31
        int lane = t & 63;
        int nt = f & 7;
        int col = nt * 16 + (lane & 15);
        int kbase = (f >> 3) * 32 + (lane >> 4) * 8;
        unsigned short* o = wpk1 + ((size_t)f * 64 + lane) * 8;
#pragma unroll
        for (int j = 0; j < 8; ++j) {
            int k = kbase + j;
            float w = (k < 64) ? W1r[k * 128 + col] : W1l[(k - 64) * 128 + col];
            o[j] = f2bf(w);
        }
    } else {
        int f = (b - nCount - nCast - 8) * 4 + (t >> 6);   // 0..19
        if (f < 20) {
            int lane = t & 63;
            int nt = f % 5;
            int col = nt * 16 + (lane & 15);       // 0..79
            int kbase = (f / 5) * 32 + (lane >> 4) * 8;
            unsigned short* o = wpk2 + ((size_t)f * 64 + lane) * 8;
#pragma unroll
            for (int j = 0; j < 8; ++j) {
                int k = kbase + j;
                float w = (col < 40) ? W2l[k * 40 + col] : W2r[k * 40 + (col - 40)];
                o[j] = f2bf(w);
            }
        }
    }
}

// ---------------- scan: column-sum hist + exclusive scan -> bbase/bcursor ----------------
__global__ void bucket_scan_kernel(const int* __restrict__ hist, int nCount,
                                   int* __restrict__ bbase, int* __restrict__ bcursor) {
    __shared__ int sd[NB];
    int t = threadIdx.x;
    int v = 0;
#pragma unroll 4
    for (int b = 0; b < nCount; ++b) v += hist[b * NB + t];
    sd[t] = v;
    __syncthreads();
    for (int off = 1; off < NB; off <<= 1) {
        int u = (t >= off) ? sd[t - off] : 0;
        __syncthreads();
        sd[t] += u;
        __syncthreads();
    }
    int ex = sd[t] - v;
    bbase[t] = ex;
    bcursor[t] = ex;
}

__global__ __launch_bounds__(256) void bucket_scatter_kernel(
        const int* __restrict__ src, const int* __restrict__ dst,
        int* __restrict__ bcursor, unsigned* __restrict__ ebuf, int E) {
    __shared__ int h[NB];
    __shared__ int base[NB];
    int t = threadIdx.x;
    int e0 = blockIdx.x * 4096;
    h[t] = 0;
    __syncthreads();
    for (int i = t; i < 4096; i += 256) {
        int e = e0 + i;
        if (e < E) atomicAdd(&h[(unsigned)dst[e] / NPB], 1);
    }
    __syncthreads();
    if (h[t] > 0) base[t] = atomicAdd(&bcursor[t], h[t]);
    h[t] = 0;
    __syncthreads();
    for (int i = t; i < 4096; i += 256) {
        int e = e0 + i;
        if (e < E) {
            unsigned d = (unsigned)dst[e];
            unsigned b = d / NPB;
            unsigned ld = d - b * NPB;
            int k = atomicAdd(&h[b], 1);
            ebuf[base[b] + k] = (ld << 17) | (unsigned)src[e];
        }
    }
}

__global__ __launch_bounds__(256) void bucket_fill_kernel(
        const unsigned* __restrict__ ebuf, const int* __restrict__ bbase,
        int* __restrict__ rowptr, int* __restrict__ csr, int E, int N) {
    __shared__ int cnt[256];
    __shared__ int sd[256];
    int b = blockIdx.x, t = threadIdx.x;
    int s0 = bbase[b];
    int s1 = (b < NB - 1) ? bbase[b + 1] : E;
    int lo = b * NPB;
    cnt[t] = 0;
    __syncthreads();
    for (int i = s0 + t; i < s1; i += 256)
        atomicAdd(&cnt[ebuf[i] >> 17], 1);
    __syncthreads();
    int v = cnt[t];
    sd[t] = v;
    __syncthreads();
    for (int off = 1; off < 256; off <<= 1) {
        int u = (t >= off) ? sd[t - off] : 0;
        __syncthreads();
        sd[t] += u;
        __syncthreads();
    }
    int ex = sd[t] - v;
    int node = lo + t;
    if (t < NPB && node < N) rowptr[node] = s0 + ex;
    cnt[t] = s0 + ex;
    __syncthreads();
    for (int i = s0 + t; i < s1; i += 256) {
        unsigned pk = ebuf[i];
        int p = atomicAdd(&cnt[pk >> 17], 1);
        csr[p] = (int)(pk & 0x1FFFFu);
    }
    if (b == NB - 1 && t == 0) rowptr[N] = E;
}

// ---------------- agg1: 8 edges/wave-instr, 32 edges in flight; bf16 in/out ----------------

__global__ void agg1_kernel(const unsigned short* __restrict__ xh, const int* __restrict__ rowptr,
                            const int* __restrict__ csr, unsigned short* __restrict__ aggh, int N) {
    int wid = (blockIdx.x * blockDim.x + threadIdx.x) >> 6;
    int lane = threadIdx.x & 63;
    if (wid >= N) return;
    int beg = rowptr[wid], end = rowptr[wid + 1];
    int deg = end - beg;
    int l = lane & 7, g = lane >> 3;
    float acc[8];
#pragma unroll
    for (int k = 0; k < 8; ++k) acc[k] = 0.f;
    int jmax = (deg + 7) >> 3;
    for (int j = 0; j < jmax; j += 4) {
        int s[4]; float w[4];
#pragma unroll
        for (int u = 0; u < 4; ++u) {
            int slot = (j + u) * 8 + g;
            int e = beg + slot;
            e = (e < end) ? e : (end - 1);
            s[u] = csr[e];
            w[u] = (slot < deg) ? 1.f : 0.f;
        }
#pragma unroll
        for (int u = 0; u < 4; ++u) {
            uint4 v = *(const uint4*)(xh + (size_t)s[u] * D0 + l * 8);
            float f0 = __uint_as_float(v.x << 16), f1 = __uint_as_float(v.x & 0xffff0000u);
            float f2 = __uint_as_float(v.y << 16), f3 = __uint_as_float(v.y & 0xffff0000u);
            float f4 = __uint_as_float(v.z << 16), f5 = __uint_as_float(v.z & 0xffff0000u);
            float f6 = __uint_as_float(v.w << 16), f7 = __uint_as_float(v.w & 0xffff0000u);
            acc[0] = fmaf(w[u], f0, acc[0]); acc[1] = fmaf(w[u], f1, acc[1]);
            acc[2] = fmaf(w[u], f2, acc[2]); acc[3] = fmaf(w[u], f3, acc[3]);
            acc[4] = fmaf(w[u], f4, acc[4]); acc[5] = fmaf(w[u], f5, acc[5]);
            acc[6] = fmaf(w[u], f6, acc[6]); acc[7] = fmaf(w[u], f7, acc[7]);
        }
    }
#pragma unroll
    for (int off = 8; off <= 32; off <<= 1) {
#pragma unroll
        for (int k = 0; k < 8; ++k) acc[k] += __shfl_xor(acc[k], off);
    }
    float inv = 1.f / (float)max(deg, 1);
    if (g == 0) {
        unsigned o0 = (unsigned)f2bf(acc[0] * inv) | ((unsigned)f2bf(acc[1] * inv) << 16);
        unsigned o1 = (unsigned)f2bf(acc[2] * inv) | ((unsigned)f2bf(acc[3] * inv) << 16);
        unsigned o2 = (unsigned)f2bf(acc[4] * inv) | ((unsigned)f2bf(acc[5] * inv) << 16);
        unsigned o3 = (unsigned)f2bf(acc[6] * inv) | ((unsigned)f2bf(acc[7] * inv) << 16);
        uint4 pk; pk.x = o0; pk.y = o1; pk.z = o2; pk.w = o3;
        *(uint4*)(aggh + (size_t)wid * D0 + l * 8) = pk;
    }
}

// ---------------- agg2 + log_softmax (fused); p2 gathered as bf16 (80B/edge) ----------------

__global__ void agg2_kernel(const unsigned short* __restrict__ p2h, const float* __restrict__ r2,
                            const int* __restrict__ rowptr, const int* __restrict__ csr,
                            float* __restrict__ out, float* __restrict__ out2, int N) {
    int wid = (blockIdx.x * blockDim.x + threadIdx.x) >> 6;
    int lane = threadIdx.x & 63;
    if (wid >= N) return;
    int beg = rowptr[wid], end = rowptr[wid + 1];
    int deg = end - beg;
    int g = lane / 10;            // 0..6 (g==6 idle)
    int l = lane - g * 10;        // 0..9
    bool gv = g < 6;
    float ax = 0.f, ay = 0.f, az = 0.f, aw = 0.f;
    int jmax = (deg + 5) / 6;
    for (int j = 0; j < jmax; j += 4) {
        int s[4]; float w[4];
#pragma unroll
        for (int u = 0; u < 4; ++u) {
            int slot = (j + u) * 6 + g;
            int e = beg + slot;
            e = (e < end) ? e : (end - 1);
            s[u] = csr[e];
            w[u] = (gv && slot < deg) ? 1.f : 0.f;
        }
#pragma unroll
        for (int u = 0; u < 4; ++u) {
            uint2 v = *(const uint2*)(p2h + (size_t)s[u] * D2 + l * 4);
            float f0 = __uint_as_float(v.x << 16), f1 = __uint_as_float(v.x & 0xffff0000u);
            float f2 = __uint_as_float(v.y << 16), f3 = __uint_as_float(v.y & 0xffff0000u);
            ax = fmaf(w[u], f0, ax); ay = fmaf(w[u], f1, ay);
            az = fmaf(w[u], f2, az); aw = fmaf(w[u], f3, aw);
        }
    }
    {
        float bx = __shfl(ax, lane + 30), by = __shfl(ay, lane + 30),
              bz = __shfl(az, lane + 30), bw = __shfl(aw, lane + 30);
        if (g < 3) { ax += bx; ay += by; az += bz; aw += bw; }
        bx = __shfl(ax, lane + 20); by = __shfl(ay, lane + 20);
        bz = __shfl(az, lane + 20); bw = __shfl(aw, lane + 20);
        if (g == 0) { ax += bx; ay += by; az += bz; aw += bw; }
        bx = __shfl(ax, lane + 10); by = __shfl(ay, lane + 10);
        bz = __shfl(az, lane + 10); bw = __shfl(aw, lane + 10);
        if (g == 0) { ax += bx; ay += by; az += bz; aw += bw; }
    }
    float inv = 1.f / (float)max(deg, 1);
    bool wr = (lane < 10);
    float4 h2;
    if (wr) {
        float4 rr = *(const float4*)(r2 + (size_t)wid * D2 + lane * 4);
        h2.x = rr.x + ax * inv; h2.y = rr.y + ay * inv;
        h2.z = rr.z + az * inv; h2.w = rr.w + aw * inv;
        *(float4*)(out + (size_t)wid * D2 + lane * 4) = h2;
    }
    float m = wr ? fmaxf(fmaxf(h2.x, h2.y), fmaxf(h2.z, h2.w)) : -INFINITY;
#pragma unroll
    for (int off = 1; off < 64; off <<= 1) m = fmaxf(m, __shfl_xor(m, off));
    float s = 0.f;
    if (wr) s = expf(h2.x - m) + expf(h2.y - m) + expf(h2.z - m) + expf(h2.w - m);
#pragma unroll
    for (int off = 1; off < 64; off <<= 1) s += __shfl_xor(s, off);
    if (wr) {
        float lg = m + logf(s);
        float4 o; o.x = h2.x - lg; o.y = h2.y - lg; o.z = h2.z - lg; o.w = h2.w - lg;
        *(float4*)(out2 + (size_t)wid * D2 + lane * 4) = o;
    }
}

// ---------------- GEMM 1 (MFMA): h = relu([x|agg]@[W1r;W1l] + b1), bf16 in/out ----------------
__global__ __launch_bounds__(256) void gemm1_mfma(
        const unsigned short* __restrict__ xh, const unsigned short* __restrict__ aggh,
        const unsigned short* __restrict__ Wpk, const float* __restrict__ b1,
        unsigned short* __restrict__ h, int N) {
    __shared__ __align__(16) unsigned short As[128 * 136];  // [row][k], +8 pad
    int t = threadIdx.x;
    int r0 = blockIdx.x * 128;
    for (int i = t; i < 2048; i += 256) {
        int r = i >> 4, c = i & 15;
        int gr = r0 + r; gr = (gr < N) ? gr : (N - 1);
        uint4 v = (c < 8) ? ((const uint4*)(xh + (size_t)gr * 64))[c]
                          : ((const uint4*)(aggh + (size_t)gr * 64))[c - 8];
        *(uint4*)(As + r * 136 + c * 8) = v;
    }
    __syncthreads();
    int w = t >> 6, lane = t & 63;
    int l15 = lane & 15, q = lane >> 4;
    f32x4 zero = {0.f, 0.f, 0.f, 0.f};
    f32x4 acc[2][8];
#pragma unroll
    for (int rt = 0; rt < 2; ++rt)
#pragma unroll
        for (int nt = 0; nt < 8; ++nt) acc[rt][nt] = zero;
    const unsigned short* abase = As + (w * 32 + l15) * 136 + q * 8;
#pragma unroll
    for (int ks = 0; ks < 4; ++ks) {
        s16x8 a0 = *(const s16x8*)(abase + ks * 32);
        s16x8 a1 = *(const s16x8*)(abase + 16 * 136 + ks * 32);
        s16x8 b[8];
#pragma unroll
        for (int nt = 0; nt < 8; ++nt)
            b[nt] = *(const s16x8*)(Wpk + ((size_t)(ks * 8 + nt) * 64 + lane) * 8);
#pragma unroll
        for (int nt = 0; nt < 8; ++nt) {
            acc[0][nt] = __builtin_amdgcn_mfma_f32_16x16x32_bf16(a0, b[nt], acc[0][nt], 0, 0, 0);
            acc[1][nt] = __builtin_amdgcn_mfma_f32_16x16x32_bf16(a1, b[nt], acc[1][nt], 0, 0, 0);
        }
    }
    int rbase = r0 + w * 32 + q * 4;
#pragma unroll
    for (int nt = 0; nt < 8; ++nt) {
        int col = nt * 16 + l15;
        float bias = b1[col];
#pragma unroll
        for (int rt = 0; rt < 2; ++rt) {
#pragma unroll
            for (int reg = 0; reg < 4; ++reg) {
                int row = rbase + rt * 16 + reg;
                if (row < N)
                    h[(size_t)row * 128 + col] = f2bf(fmaxf(acc[rt][nt][reg] + bias, 0.f));
            }
        }
    }
}

// ---------------- GEMM 2 (MFMA): p2h(bf16) = h@W2l, r2(f32) = h@W2r + b2 ----------------
__global__ __launch_bounds__(256) void gemm2_mfma(
        const unsigned short* __restrict__ hq, const unsigned short* __restrict__ Wpk,
        const float* __restrict__ b2,
        unsigned short* __restrict__ p2h, float* __restrict__ r2, int N) {
    __shared__ __align__(16) unsigned short As[128 * 136];
    int t = threadIdx.x;
    int r0 = blockIdx.x * 128;
    for (int i = t; i < 2048; i += 256) {
        int r = i >> 4, c = i & 15;
        int gr = r0 + r; gr = (gr < N) ? gr : (N - 1);
        uint4 v = ((const uint4*)(hq + (size_t)gr * 128))[c];
        *(uint4*)(As + r * 136 + c * 8) = v;
    }
    __syncthreads();
    int w = t >> 6, lane = t & 63;
    int l15 = lane & 15, q = lane >> 4;
    f32x4 zero = {0.f, 0.f, 0.f, 0.f};
    f32x4 acc[2][5];
#pragma unroll
    for (int rt = 0; rt < 2; ++rt)
#pragma unroll
        for (int nt = 0; nt < 5; ++nt) acc[rt][nt] = zero;
    const unsigned short* abase = As + (w * 32 + l15) * 136 + q * 8;
#pragma unroll
    for (int ks = 0; ks < 4; ++ks) {
        s16x8 a0 = *(const s16x8*)(abase + ks * 32);
        s16x8 a1 = *(const s16x8*)(abase + 16 * 136 + ks * 32);
        s16x8 b[5];
#pragma unroll
        for (int nt = 0; nt < 5; ++nt)
            b[nt] = *(const s16x8*)(Wpk + ((size_t)(ks * 5 + nt) * 64 + lane) * 8);
#pragma unroll
        for (int nt = 0; nt < 5; ++nt) {
            acc[0][nt] = __builtin_amdgcn_mfma_f32_16x16x32_bf16(a0, b[nt], acc[0][nt], 0, 0, 0);
            acc[1][nt] = __builtin_amdgcn_mfma_f32_16x16x32_bf16(a1, b[nt], acc[1][nt], 0, 0, 0);
        }
    }
    int rbase = r0 + w * 32 + q * 4;
#pragma unroll
    for (int nt = 0; nt < 5; ++nt) {
        int col = nt * 16 + l15;   // 0..79
        bool isp = col < 40;
        int oc = isp ? col : (col - 40);
        float bias = isp ? 0.f : b2[oc];
#pragma unroll
        for (int rt = 0; rt < 2; ++rt) {
#pragma unroll
            for (int reg = 0; reg < 4; ++reg) {
                int row = rbase + rt * 16 + reg;
                if (row < N) {
                    float v = acc[rt][nt][reg] + bias;
                    if (isp) p2h[(size_t)row * 40 + oc] = f2bf(v);
                    else     r2[(size_t)row * 40 + oc] = v;
                }
            }
        }
    }
}

// ---------------- launch ----------------

extern "C" void kernel_launch(void* const* d_in, const int* in_sizes, int n_in,
                              void* d_out, int out_size, void* d_ws, size_t ws_size,
                              hipStream_t stream) {
    const float* x   = (const float*)d_in[0];
    const int*   ei  = (const int*)d_in[1];
    const float* W1l = (const float*)d_in[2];
    const float* W1r = (const float*)d_in[3];
    const float* b1  = (const float*)d_in[4];
    const float* W2l = (const float*)d_in[5];
    const float* W2r = (const float*)d_in[6];
    const float* b2  = (const float*)d_in[7];
    float* out = (float*)d_out;

    const int N = N_NODES;
    const int E = in_sizes[1] / 2;
    const int* src = ei;
    const int* dst = ei + E;

    char* p = (char*)d_ws;
    auto alloc = [&](size_t bytes) -> void* {
        void* r = (void*)p;
        p += (bytes + 255) & ~(size_t)255;
        return r;
    };
    const int nCount = (E + 2047) / 2048;          // 391
    const int nCast  = (N * D0) / 1024;            // 3125 (exact)

    int*      rowptr  = (int*)alloc((size_t)(N + 1) * 4);
    int*      csr     = (int*)alloc((size_t)E * 4);
    unsigned* ebuf    = (unsigned*)alloc((size_t)E * 4);
    int*      hist    = (int*)alloc((size_t)nCount * NB * 4);
    int*      bbase   = (int*)alloc(NB * 4);
    int*      bcursor = (int*)alloc(NB * 4);
    unsigned short* xh    = (unsigned short*)alloc((size_t)N * D0 * 2);
    unsigned short* aggh  = (unsigned short*)alloc((size_t)N * D0 * 2);
    unsigned short* hbuf  = (unsigned short*)alloc((size_t)N * D1 * 2);
    unsigned short* wpk1  = (unsigned short*)alloc((size_t)32 * 64 * 8 * 2);
    unsigned short* wpk2  = (unsigned short*)alloc((size_t)20 * 64 * 8 * 2);
    unsigned short* p2h   = (unsigned short*)alloc((size_t)N * D2 * 2);
    float* r2buf = (float*)alloc((size_t)N * D2 * 4);

    // prep (hist + cast + pack) -> scan -> scatter -> fill
    prep_kernel<<<nCount + nCast + 8 + 5, 256, 0, stream>>>(
        x, dst, W1l, W1r, W2l, W2r, xh, hist, wpk1, wpk2, E, nCount, nCast);
    bucket_scan_kernel<<<1, NB, 0, stream>>>(hist, nCount, bbase, bcursor);
    bucket_scatter_kernel<<<(E + 4095) / 4096, 256, 0, stream>>>(src, dst, bcursor, ebuf, E);
    bucket_fill_kernel<<<NB, 256, 0, stream>>>(ebuf, bbase, rowptr, csr, E, N);

    // layer 1
    agg1_kernel<<<(N * 64 + 255) / 256, 256, 0, stream>>>(xh, rowptr, csr, aggh, N);
    gemm1_mfma<<<(N + 127) / 128, 256, 0, stream>>>(xh, aggh, wpk1, b1, hbuf, N);

    // layer 2: project first (linearity), gather 40-dim bf16, fused log_softmax
    gemm2_mfma<<<(N + 127) / 128, 256, 0, stream>>>(hbuf, wpk2, b2, p2h, r2buf, N);
    agg2_kernel<<<(N * 64 + 255) / 256, 256, 0, stream>>>(p2h, r2buf, rowptr, csr,
                                                          out, out + (size_t)N * D2, N);
}